// Round 1
// baseline (16893.214 us; speedup 1.0000x reference)
//
#include <hip/hip_runtime.h>
#include <hip/hip_bf16.h>

#define B_ 128
#define T_ 512
#define I_ 64
#define H_ 1024
#define O_ 12
#define HB_ (H_ * B_)   // 131072 elements per timestep of hs
#define NBLK 256        // persistent blocks; 4 rows of W_hh each

// ---------------- bf16 helpers (fallback hs storage if ws is small) --------
__device__ __forceinline__ float bf2f(unsigned short s) {
  unsigned u = ((unsigned)s) << 16; float f; __builtin_memcpy(&f, &u, 4); return f;
}
__device__ __forceinline__ unsigned short f2bf(float f) {
  unsigned u; __builtin_memcpy(&u, &f, 4);
  u += 0x7fffu + ((u >> 16) & 1u);   // round-to-nearest-even (inputs are finite: tanh output)
  return (unsigned short)(u >> 16);
}
__device__ __forceinline__ float2 loadH2(const float* p) { return *(const float2*)p; }
__device__ __forceinline__ float2 loadH2(const unsigned short* p) {
  unsigned u = *(const unsigned*)p;
  return make_float2(bf2f((unsigned short)(u & 0xffffu)), bf2f((unsigned short)(u >> 16)));
}
__device__ __forceinline__ float loadH1(const float* p) { return *p; }
__device__ __forceinline__ float loadH1(const unsigned short* p) { return bf2f(*p); }
__device__ __forceinline__ void storeH(float* p, float v) { *p = v; }
__device__ __forceinline__ void storeH(unsigned short* p, float v) { *p = f2bf(v); }

// ---------------- hierarchical monotonic grid barrier ----------------------
// bar layout (uints): [g*64] g=0..7 group counters (256B apart), [512] root,
// [576] release epoch. Zeroed by prep_misc every launch.
__device__ __forceinline__ void gridbar(unsigned* bar, int e) {
  __syncthreads();                       // all waves done; vmcnt drained by barrier
  if (threadIdx.x == 0) {
    __threadfence();                     // release: wb XCD L2 -> LLC (covers block's hs stores)
    const int g = (int)(blockIdx.x >> 5);  // 8 groups of 32 blocks
    unsigned v = __hip_atomic_fetch_add(&bar[g * 64], 1u, __ATOMIC_ACQ_REL,
                                        __HIP_MEMORY_SCOPE_AGENT);
    if (v == (unsigned)(e * 32 - 1)) {   // last arriver of this group this epoch
      unsigned r = __hip_atomic_fetch_add(&bar[512], 1u, __ATOMIC_ACQ_REL,
                                          __HIP_MEMORY_SCOPE_AGENT);
      if (r == (unsigned)(e * 8 - 1)) {  // last group globally -> release
        __hip_atomic_store(&bar[576], (unsigned)e, __ATOMIC_RELEASE,
                           __HIP_MEMORY_SCOPE_AGENT);
      }
    }
    // relaxed agent-scope poll (no cache-wide invalidate per poll)
    while (__hip_atomic_load(&bar[576], __ATOMIC_RELAXED,
                             __HIP_MEMORY_SCOPE_AGENT) < (unsigned)e) {
      __builtin_amdgcn_s_sleep(2);
    }
    __threadfence();                     // acquire: inv L1/L2 so hs reads are fresh
  }
  __syncthreads();
}

// ---------------- prep: transpose x[b][t*64+i] -> xT[(t*64+i)][b] ----------
__global__ void transpose_x(const float* __restrict__ x, float* __restrict__ xT) {
  __shared__ float tile[32][33];
  const int c0 = blockIdx.x * 32;        // column = t*64+i  (32768 total)
  const int r0 = blockIdx.y * 32;        // row = b (128 total)
  const int lx = threadIdx.x & 31;
  const int ly = threadIdx.x >> 5;       // 0..7
  for (int yy = ly; yy < 32; yy += 8)
    tile[yy][lx] = x[(size_t)(r0 + yy) * (T_ * I_) + c0 + lx];
  __syncthreads();
  for (int yy = ly; yy < 32; yy += 8)
    xT[(size_t)(c0 + yy) * B_ + r0 + lx] = tile[lx][yy];
}

// ---------------- prep: barrier zero + W_out transposed/padded -------------
// WoT[k][16]: slots 0..5 = W_out[0..5][k], slots 8..13 = W_out[6..11][k], rest 0
__global__ void prep_misc(const float* __restrict__ W_out, float* __restrict__ WoT,
                          unsigned* __restrict__ bar) {
  const int idx = blockIdx.x * 256 + threadIdx.x;    // 64 blocks -> 16384 threads
  if (idx < 1024) bar[idx] = 0u;
  const int k = idx >> 4, s = idx & 15;
  float v = 0.0f;
  if (s < 6)                 v = W_out[s * H_ + k];
  else if (s >= 8 && s < 14) v = W_out[(s - 2) * H_ + k];
  WoT[idx] = v;
}

// ---------------- persistent recurrence kernel -----------------------------
// Block bid owns rows [4*bid, 4*bid+4) of W_hh (16KB LDS, resident all steps).
// hs layout: [t][k][b] so h loads are lane-coalesced float2.
// Wave w handles k in [256w,256w+256) and i in [16w,16w+16); partials combined in LDS.
template <typename HS>
__global__ __launch_bounds__(256, 1) void rnn_persist(
    const float* __restrict__ W_ih, const float* __restrict__ W_hh,
    const float* __restrict__ b_ih, const float* __restrict__ b_hh,
    const float* __restrict__ xT, HS* __restrict__ hs, unsigned* __restrict__ bar)
{
  __shared__ float4 wt[H_];       // wt[k] = {W_hh[r0+0..3][k]}   16 KB
  __shared__ float4 wih[I_];      // wih[i] = {W_ih[r0+0..3][i]}   1 KB
  __shared__ float part[4][512];  // per-wave partial sums         8 KB
  __shared__ float bias4[4];

  const int tid  = threadIdx.x;
  const int bid  = blockIdx.x;
  const int wave = tid >> 6;
  const int lane = tid & 63;
  const int b0   = lane * 2;      // batch pair
  const int r0   = bid * 4;

  for (int r = 0; r < 4; ++r)
    for (int k = tid; k < H_; k += 256)
      ((float*)&wt[k])[r] = W_hh[(size_t)(r0 + r) * H_ + k];
  for (int r = 0; r < 4; ++r)
    for (int i = tid; i < I_; i += 256)
      ((float*)&wih[i])[r] = W_ih[(r0 + r) * I_ + i];
  if (tid < 4) bias4[tid] = b_ih[r0 + tid] + b_hh[r0 + tid];
  __syncthreads();

  const int k0 = wave * 256;
  const int i0 = wave * 16;

  for (int t = 0; t < T_; ++t) {
    float a0=0.f,a1=0.f,a2=0.f,a3=0.f,a4=0.f,a5=0.f,a6=0.f,a7=0.f;
    if (t > 0) {
      const HS* hp = hs + (size_t)(t - 1) * HB_ + b0;
      #pragma unroll 4
      for (int k = k0; k < k0 + 256; ++k) {
        float2 hv = loadH2(hp + k * B_);     // coalesced, each elem read once/block
        float4 w  = wt[k];                   // wave-uniform LDS broadcast
        a0 += w.x * hv.x; a1 += w.x * hv.y;
        a2 += w.y * hv.x; a3 += w.y * hv.y;
        a4 += w.z * hv.x; a5 += w.z * hv.y;
        a6 += w.w * hv.x; a7 += w.w * hv.y;
      }
    }
    {
      const float* xp = xT + (size_t)t * (I_ * B_) + b0;
      #pragma unroll
      for (int i = i0; i < i0 + 16; ++i) {
        float2 xv = *(const float2*)(xp + i * B_);
        float4 w  = wih[i];
        a0 += w.x * xv.x; a1 += w.x * xv.y;
        a2 += w.y * xv.x; a3 += w.y * xv.y;
        a4 += w.z * xv.x; a5 += w.z * xv.y;
        a6 += w.w * xv.x; a7 += w.w * xv.y;
      }
    }
    part[wave][0 * 128 + b0] = a0; part[wave][0 * 128 + b0 + 1] = a1;
    part[wave][1 * 128 + b0] = a2; part[wave][1 * 128 + b0 + 1] = a3;
    part[wave][2 * 128 + b0] = a4; part[wave][2 * 128 + b0 + 1] = a5;
    part[wave][3 * 128 + b0] = a6; part[wave][3 * 128 + b0 + 1] = a7;
    __syncthreads();

    HS* ho = hs + (size_t)t * HB_;
    #pragma unroll
    for (int o = tid; o < 512; o += 256) {
      float s = part[0][o] + part[1][o] + part[2][o] + part[3][o] + bias4[o >> 7];
      storeH(ho + (r0 + (o >> 7)) * B_ + (o & 127), tanhf(s));
    }
    if (t < T_ - 1) gridbar(bar, t + 1);   // entry __syncthreads also guards `part` reuse
  }
}

// ---------------- output projection: out[b][t][o] = hs[t][:,b]·W_out[o] + b_out
template <typename HS>
__global__ __launch_bounds__(256, 1) void out_proj(
    const HS* __restrict__ hs, const float* __restrict__ WoT,
    const float* __restrict__ b_out, float* __restrict__ out)
{
  const int t   = blockIdx.x;
  const int tid = threadIdx.x;
  const int b   = tid & 127;
  const int oh  = tid >> 7;     // wave-uniform o-half (0: o 0..5, 1: o 6..11)
  float acc0 = b_out[oh * 6 + 0], acc1 = b_out[oh * 6 + 1], acc2 = b_out[oh * 6 + 2];
  float acc3 = b_out[oh * 6 + 3], acc4 = b_out[oh * 6 + 4], acc5 = b_out[oh * 6 + 5];
  const HS* hp = hs + (size_t)t * HB_ + b;
  const float4* W4 = (const float4*)WoT;
  #pragma unroll 4
  for (int k = 0; k < H_; ++k) {
    float  hv = loadH1(hp + k * B_);          // lane-coalesced
    float4 wa = W4[k * 4 + oh * 2];           // wave-uniform -> scalar loads
    float4 wb = W4[k * 4 + oh * 2 + 1];
    acc0 += wa.x * hv; acc1 += wa.y * hv; acc2 += wa.z * hv;
    acc3 += wa.w * hv; acc4 += wb.x * hv; acc5 += wb.y * hv;
  }
  float* op = out + ((size_t)b * T_ + t) * O_ + oh * 6;
  op[0] = acc0; op[1] = acc1; op[2] = acc2; op[3] = acc3; op[4] = acc4; op[5] = acc5;
}

// ---------------- host ------------------------------------------------------
extern "C" void kernel_launch(void* const* d_in, const int* in_sizes, int n_in,
                              void* d_out, int out_size, void* d_ws, size_t ws_size,
                              hipStream_t stream)
{
  const float* x     = (const float*)d_in[0];
  const float* W_ih  = (const float*)d_in[1];
  const float* W_hh  = (const float*)d_in[2];
  const float* b_ih  = (const float*)d_in[3];
  const float* b_hh  = (const float*)d_in[4];
  const float* W_out = (const float*)d_in[5];
  const float* b_out = (const float*)d_in[6];
  float* out = (float*)d_out;

  const size_t hs_f32  = (size_t)T_ * HB_ * 4;       // 268 MB
  const size_t hs_bf16 = (size_t)T_ * HB_ * 2;       // 134 MB fallback
  const size_t xT_sz   = (size_t)T_ * I_ * B_ * 4;   // 16.8 MB
  const size_t WoT_sz  = (size_t)H_ * 16 * 4;        // 64 KB
  const size_t bar_sz  = 4096;
  const bool f32 = ws_size >= hs_f32 + xT_sz + WoT_sz + bar_sz;
  const size_t hs_sz = f32 ? hs_f32 : hs_bf16;

  char* base = (char*)d_ws;
  void*     hs  = (void*)base;
  float*    xT  = (float*)(base + hs_sz);
  float*    WoT = (float*)(base + hs_sz + xT_sz);
  unsigned* bar = (unsigned*)(base + hs_sz + xT_sz + WoT_sz);

  transpose_x<<<dim3(1024, 4), 256, 0, stream>>>(x, xT);
  prep_misc<<<64, 256, 0, stream>>>(W_out, WoT, bar);
  if (f32) {
    rnn_persist<float><<<NBLK, 256, 0, stream>>>(W_ih, W_hh, b_ih, b_hh, xT,
                                                 (float*)hs, bar);
    out_proj<float><<<T_, 256, 0, stream>>>((const float*)hs, WoT, b_out, out);
  } else {
    rnn_persist<unsigned short><<<NBLK, 256, 0, stream>>>(W_ih, W_hh, b_ih, b_hh, xT,
                                                          (unsigned short*)hs, bar);
    out_proj<unsigned short><<<T_, 256, 0, stream>>>((const unsigned short*)hs, WoT,
                                                     b_out, out);
  }
}

// Round 2
// 8165.189 us; speedup vs baseline: 2.0689x; 2.0689x over previous
//
#include <hip/hip_runtime.h>
#include <hip/hip_bf16.h>

#define B_ 128
#define T_ 512
#define I_ 64
#define H_ 1024
#define O_ 12
#define HSTEP (H_ * B_)   // 131072 bf16 elements per timestep of hP
#define XSTEP (I_ * B_)   // 8192 bf16 elements per timestep of each xP plane

typedef __attribute__((ext_vector_type(8))) short bf16x8;
typedef __attribute__((ext_vector_type(4))) float f32x4;

#define MFMA16 __builtin_amdgcn_mfma_f32_16x16x32_bf16

__device__ __forceinline__ float bf2f(unsigned short s) {
  unsigned u = ((unsigned)s) << 16; float f; __builtin_memcpy(&f, &u, 4); return f;
}
__device__ __forceinline__ unsigned short f2bf(float f) {
  unsigned u; __builtin_memcpy(&u, &f, 4);
  u += 0x7fffu + ((u >> 16) & 1u);   // RNE (finite inputs only here)
  return (unsigned short)(u >> 16);
}

// ---- per-batch-group barrier: 32 blocks share group g; monotonic epochs ----
// bar[g*64] = arrival counter, bar[g*64+32] = release epoch. Zeroed each launch.
__device__ __forceinline__ void gridbar_group(unsigned* bar, int g, int e) {
  __syncthreads();                      // all waves' hP stores issued; vmcnt drained
  if (threadIdx.x == 0) {
    __threadfence();                    // release: XCD L2 writeback covers block's stores
    unsigned v = __hip_atomic_fetch_add(&bar[g * 64], 1u, __ATOMIC_ACQ_REL,
                                        __HIP_MEMORY_SCOPE_AGENT);
    if (v == (unsigned)(e * 32 - 1))    // last of 32 arrivers this epoch
      __hip_atomic_store(&bar[g * 64 + 32], (unsigned)e, __ATOMIC_RELEASE,
                         __HIP_MEMORY_SCOPE_AGENT);
    while (__hip_atomic_load(&bar[g * 64 + 32], __ATOMIC_RELAXED,
                             __HIP_MEMORY_SCOPE_AGENT) < (unsigned)e)
      __builtin_amdgcn_s_sleep(1);
    __threadfence();                    // acquire: invalidate so hP reads are fresh
  }
  __syncthreads();
}

// ---- prep: x[b][t][i] fp32 -> pack-layout bf16 hi/lo planes xP[t][i/8][b][i%8]
__global__ void prep_xp(const float* __restrict__ x,
                        unsigned short* __restrict__ xPhi,
                        unsigned short* __restrict__ xPlo) {
  const int t = blockIdx.x;
  for (int u = threadIdx.x; u < 1024; u += 256) {   // u = ib*128 + b
    const int ib = u >> 7, b = u & 127;
    const float* src = x + ((size_t)b * T_ + t) * I_ + ib * 8;
    bf16x8 hi, lo;
    #pragma unroll
    for (int j = 0; j < 8; ++j) {
      float v = src[j];
      unsigned short h = f2bf(v);
      hi[j] = (short)h;
      lo[j] = (short)f2bf(v - bf2f(h));
    }
    *(bf16x8*)(xPhi + ((size_t)t * 1024 + u) * 8) = hi;
    *(bf16x8*)(xPlo + ((size_t)t * 1024 + u) * 8) = lo;
  }
}

// ---- prep: zero barrier + W_out transposed/padded WoT[k][16] ----
__global__ void prep_misc(const float* __restrict__ W_out, float* __restrict__ WoT,
                          unsigned* __restrict__ bar) {
  const int idx = blockIdx.x * 256 + threadIdx.x;   // 64 blocks -> 16384 threads
  if (idx < 1024) bar[idx] = 0u;
  const int k = idx >> 4, s = idx & 15;
  float v = 0.0f;
  if (s < 6)                 v = W_out[s * H_ + k];
  else if (s >= 8 && s < 14) v = W_out[(s - 2) * H_ + k];
  WoT[idx] = v;
}

// ---- persistent MFMA recurrence ----
// Block bid: g = bid>>5 (batch group, 16 batches), rg = bid&31 (32 rows).
// Waves split K=1024 into quarters; W_hh frags live in VGPRs as bf16 hi/lo.
// Layouts (16x16x32 bf16 MFMA): A[m=lane&15][k=quad*8+j]; B[k=quad*8+j][n=lane&15];
// C/D: n=lane&15, m=quad*4+reg.
__global__ __launch_bounds__(256, 1) void rnn_mfma(
    const float* __restrict__ W_ih, const float* __restrict__ W_hh,
    const float* __restrict__ b_ih, const float* __restrict__ b_hh,
    const unsigned short* __restrict__ xPhi, const unsigned short* __restrict__ xPlo,
    unsigned short* __restrict__ hP, unsigned* __restrict__ bar)
{
  __shared__ float part[4][512];
  __shared__ float biasS[32];
  const int tid = threadIdx.x, bid = blockIdx.x;
  const int wave = tid >> 6, lane = tid & 63, quad = lane >> 4, ln = lane & 15;
  const int g = bid >> 5, rg = bid & 31;
  const int r0 = rg * 32, b0 = g * 16;
  if (tid < 32) biasS[tid] = b_ih[r0 + tid] + b_hh[r0 + tid];

  // A-frags for W_hh (hi/lo split -> full fp32-ish W precision), once.
  bf16x8 ahhi[2][8], ahlo[2][8];
  #pragma unroll
  for (int mt = 0; mt < 2; ++mt)
    #pragma unroll
    for (int kt = 0; kt < 8; ++kt) {
      const float* wp = W_hh + (size_t)(r0 + mt * 16 + ln) * H_
                        + wave * 256 + kt * 32 + quad * 8;
      #pragma unroll
      for (int j = 0; j < 8; ++j) {
        float v = wp[j];
        unsigned short h = f2bf(v);
        ahhi[mt][kt][j] = (short)h;
        ahlo[mt][kt][j] = (short)f2bf(v - bf2f(h));
      }
    }
  // A-frags for W_ih: wave w<2 owns x K-tile ktx=w (i in [32w,32w+32)).
  bf16x8 axhi[2], axlo[2];
  if (wave < 2)
    #pragma unroll
    for (int mt = 0; mt < 2; ++mt) {
      const float* wp = W_ih + (size_t)(r0 + mt * 16 + ln) * I_
                        + wave * 32 + quad * 8;
      #pragma unroll
      for (int j = 0; j < 8; ++j) {
        float v = wp[j];
        unsigned short h = f2bf(v);
        axhi[mt][j] = (short)h;
        axlo[mt][j] = (short)f2bf(v - bf2f(h));
      }
    }
  __syncthreads();

  const int bcol = b0 + ln;

  for (int t = 0; t < T_; ++t) {
    f32x4 acc0 = {0.f, 0.f, 0.f, 0.f}, acc1 = {0.f, 0.f, 0.f, 0.f};

    // x contribution: Whi*xhi + Whi*xlo + Wlo*xhi  (waves 0,1 only)
    if (wave < 2) {
      const size_t xo = (((size_t)t * 8 + wave * 4 + quad) * B_ + bcol) * 8;
      bf16x8 bxh = *(const bf16x8*)(xPhi + xo);
      bf16x8 bxl = *(const bf16x8*)(xPlo + xo);
      acc0 = MFMA16(axhi[0], bxh, acc0, 0, 0, 0);
      acc1 = MFMA16(axhi[1], bxh, acc1, 0, 0, 0);
      acc0 = MFMA16(axhi[0], bxl, acc0, 0, 0, 0);
      acc1 = MFMA16(axhi[1], bxl, acc1, 0, 0, 0);
      acc0 = MFMA16(axlo[0], bxh, acc0, 0, 0, 0);
      acc1 = MFMA16(axlo[1], bxh, acc1, 0, 0, 0);
    }

    // h contribution: 8 independent 16B B-frag loads, then 32 MFMAs
    if (t > 0) {
      const unsigned short* hprev = hP + (size_t)(t - 1) * HSTEP;
      bf16x8 bh[8];
      #pragma unroll
      for (int kt = 0; kt < 8; ++kt)
        bh[kt] = *(const bf16x8*)(hprev
                   + ((size_t)((wave * 32 + kt * 4 + quad) * B_) + bcol) * 8);
      #pragma unroll
      for (int kt = 0; kt < 8; ++kt) {
        acc0 = MFMA16(ahhi[0][kt], bh[kt], acc0, 0, 0, 0);
        acc1 = MFMA16(ahhi[1][kt], bh[kt], acc1, 0, 0, 0);
        acc0 = MFMA16(ahlo[0][kt], bh[kt], acc0, 0, 0, 0);
        acc1 = MFMA16(ahlo[1][kt], bh[kt], acc1, 0, 0, 0);
      }
    }

    // combine K-split partials across waves via LDS
    #pragma unroll
    for (int r = 0; r < 4; ++r) {
      part[wave][r * 64 + lane]       = acc0[r];
      part[wave][(4 + r) * 64 + lane] = acc1[r];
    }
    __syncthreads();

    if (tid < 128) {   // thread (mt,l): reduce 4 regs, tanh, pack 4 bf16 -> 8B store
      const int mt = tid >> 6, l = tid & 63, q = l >> 4, n = l & 15;
      const int row4 = r0 + mt * 16 + q * 4;     // 4 consecutive rows, 8B-aligned in pack
      unsigned short o[4];
      #pragma unroll
      for (int r = 0; r < 4; ++r) {
        const int f = (mt * 4 + r) * 64 + l;
        float s = part[0][f] + part[1][f] + part[2][f] + part[3][f]
                  + biasS[mt * 16 + q * 4 + r];
        o[r] = f2bf(tanhf(s));
      }
      uint2 pk;
      pk.x = (unsigned)o[0] | ((unsigned)o[1] << 16);
      pk.y = (unsigned)o[2] | ((unsigned)o[3] << 16);
      unsigned short* dst = hP + (size_t)t * HSTEP
                            + ((size_t)(row4 >> 3) * B_ + (b0 + n)) * 8 + (row4 & 7);
      *((uint2*)dst) = pk;
    }

    if (t < T_ - 1) gridbar_group(bar, g, t + 1);  // entry sync also guards part[] reuse
  }
}

// ---- output projection from pack layout: out[b][t][o] ----
__global__ __launch_bounds__(256, 2) void out_proj(
    const unsigned short* __restrict__ hP, const float* __restrict__ WoT,
    const float* __restrict__ b_out, float* __restrict__ out)
{
  const int t = blockIdx.x;
  const int tid = threadIdx.x;
  const int b  = tid & 127;
  const int oh = tid >> 7;                 // wave-uniform output half
  float a0 = b_out[oh * 6 + 0], a1 = b_out[oh * 6 + 1], a2 = b_out[oh * 6 + 2];
  float a3 = b_out[oh * 6 + 3], a4 = b_out[oh * 6 + 4], a5 = b_out[oh * 6 + 5];
  const unsigned short* hp = hP + (size_t)t * HSTEP + (size_t)b * 8;
  const float4* W4 = (const float4*)WoT;
  for (int kb = 0; kb < 128; ++kb) {
    bf16x8 hv = *(const bf16x8*)(hp + (size_t)kb * (B_ * 8));  // 16B coalesced
    #pragma unroll
    for (int j = 0; j < 8; ++j) {
      const int k = kb * 8 + j;
      float h = bf2f((unsigned short)hv[j]);
      float4 wa = W4[k * 4 + oh * 2];       // wave-uniform
      float4 wb = W4[k * 4 + oh * 2 + 1];
      a0 += wa.x * h; a1 += wa.y * h; a2 += wa.z * h;
      a3 += wa.w * h; a4 += wb.x * h; a5 += wb.y * h;
    }
  }
  float* op = out + ((size_t)b * T_ + t) * O_ + oh * 6;
  op[0] = a0; op[1] = a1; op[2] = a2; op[3] = a3; op[4] = a4; op[5] = a5;
}

// ---- host ----
extern "C" void kernel_launch(void* const* d_in, const int* in_sizes, int n_in,
                              void* d_out, int out_size, void* d_ws, size_t ws_size,
                              hipStream_t stream)
{
  const float* x     = (const float*)d_in[0];
  const float* W_ih  = (const float*)d_in[1];
  const float* W_hh  = (const float*)d_in[2];
  const float* b_ih  = (const float*)d_in[3];
  const float* b_hh  = (const float*)d_in[4];
  const float* W_out = (const float*)d_in[5];
  const float* b_out = (const float*)d_in[6];
  float* out = (float*)d_out;

  unsigned short* hP   = (unsigned short*)d_ws;                 // 134.2 MB
  unsigned short* xPhi = hP + (size_t)T_ * HSTEP;               // 8.4 MB
  unsigned short* xPlo = xPhi + (size_t)T_ * XSTEP;             // 8.4 MB
  float*          WoT  = (float*)(xPlo + (size_t)T_ * XSTEP);   // 64 KB
  unsigned*       bar  = (unsigned*)(WoT + (size_t)H_ * 16);    // 4 KB

  prep_xp  <<<T_,  256, 0, stream>>>(x, xPhi, xPlo);
  prep_misc<<<64,  256, 0, stream>>>(W_out, WoT, bar);
  rnn_mfma <<<256, 256, 0, stream>>>(W_ih, W_hh, b_ih, b_hh, xPhi, xPlo, hP, bar);
  out_proj <<<T_,  256, 0, stream>>>(hP, WoT, b_out, out);
}

// Round 3
// 2282.382 us; speedup vs baseline: 7.4016x; 3.5775x over previous
//
#include <hip/hip_runtime.h>
#include <hip/hip_bf16.h>

#define B_ 128
#define T_ 512
#define I_ 64
#define H_ 1024
#define O_ 12
#define HSTEP (H_ * B_)   // 131072 bf16 elements per timestep of hP
#define XSTEP (I_ * B_)   // 8192 bf16 elements per timestep of each xP plane

typedef __attribute__((ext_vector_type(8))) short bf16x8;
typedef __attribute__((ext_vector_type(4))) float f32x4;

#define MFMA16 __builtin_amdgcn_mfma_f32_16x16x32_bf16

__device__ __forceinline__ float bf2f(unsigned short s) {
  unsigned u = ((unsigned)s) << 16; float f; __builtin_memcpy(&f, &u, 4); return f;
}
__device__ __forceinline__ unsigned short f2bf(float f) {
  unsigned u; __builtin_memcpy(&u, &f, 4);
  u += 0x7fffu + ((u >> 16) & 1u);   // RNE (finite inputs only here)
  return (unsigned short)(u >> 16);
}

// ---- agent-scope relaxed atomics: cache-bypassing, coherent at LLC, NO fences
__device__ __forceinline__ unsigned ldA32(const unsigned* p) {
  return __hip_atomic_load(p, __ATOMIC_RELAXED, __HIP_MEMORY_SCOPE_AGENT);
}
__device__ __forceinline__ void stA32(unsigned* p, unsigned v) {
  __hip_atomic_store(p, v, __ATOMIC_RELAXED, __HIP_MEMORY_SCOPE_AGENT);
}
__device__ __forceinline__ unsigned long long ldA64(const unsigned long long* p) {
  return __hip_atomic_load(p, __ATOMIC_RELAXED, __HIP_MEMORY_SCOPE_AGENT);
}

// ---- prep: x[b][t][i] fp32 -> pack-layout bf16 hi/lo planes xP[t][i/8][b][i%8]
__global__ void prep_xp(const float* __restrict__ x,
                        unsigned short* __restrict__ xPhi,
                        unsigned short* __restrict__ xPlo) {
  const int t = blockIdx.x;
  for (int u = threadIdx.x; u < 1024; u += 256) {   // u = ib*128 + b
    const int ib = u >> 7, b = u & 127;
    const float* src = x + ((size_t)b * T_ + t) * I_ + ib * 8;
    bf16x8 hi, lo;
    #pragma unroll
    for (int j = 0; j < 8; ++j) {
      float v = src[j];
      unsigned short h = f2bf(v);
      hi[j] = (short)h;
      lo[j] = (short)f2bf(v - bf2f(h));
    }
    *(bf16x8*)(xPhi + ((size_t)t * 1024 + u) * 8) = hi;
    *(bf16x8*)(xPlo + ((size_t)t * 1024 + u) * 8) = lo;
  }
}

// ---- prep: zero barrier flags + W_out transposed/padded WoT[k][16] ----
__global__ void prep_misc(const float* __restrict__ W_out, float* __restrict__ WoT,
                          unsigned* __restrict__ bar) {
  const int idx = blockIdx.x * 256 + threadIdx.x;   // 64 blocks -> 16384 threads
  if (idx < 1024) bar[idx] = 0u;
  const int k = idx >> 4, s = idx & 15;
  float v = 0.0f;
  if (s < 6)                 v = W_out[s * H_ + k];
  else if (s >= 8 && s < 14) v = W_out[(s - 2) * H_ + k];
  WoT[idx] = v;
}

// ---- persistent MFMA recurrence ----
// Block bid: g = bid>>5 (16 batches), rg = bid&31 (32 rows). Waves split K=1024.
// W_hh/W_ih live in VGPRs as bf16 hi/lo fragment pairs (fp32-grade W precision).
// hP is accessed ONLY via agent-scope relaxed atomics -> coherent at LLC, no
// cache-wide fences anywhere. Barrier = 32 per-block epoch flags, polled
// lane-parallel by wave 0 (no RMW chain).
__global__ __launch_bounds__(256, 1) void rnn_mfma(
    const float* __restrict__ W_ih, const float* __restrict__ W_hh,
    const float* __restrict__ b_ih, const float* __restrict__ b_hh,
    const unsigned short* __restrict__ xPhi, const unsigned short* __restrict__ xPlo,
    unsigned short* __restrict__ hP, unsigned* __restrict__ bar)
{
  __shared__ float part[4][512];
  __shared__ float biasS[32];
  const int tid = threadIdx.x, bid = blockIdx.x;
  const int wave = tid >> 6, lane = tid & 63, quad = lane >> 4, ln = lane & 15;
  const int g = bid >> 5, rg = bid & 31;
  const int r0 = rg * 32, b0 = g * 16;
  if (tid < 32) biasS[tid] = b_ih[r0 + tid] + b_hh[r0 + tid];

  // A-frags for W_hh (hi/lo split), loaded once.
  bf16x8 ahhi[2][8], ahlo[2][8];
  #pragma unroll
  for (int mt = 0; mt < 2; ++mt)
    #pragma unroll
    for (int kt = 0; kt < 8; ++kt) {
      const float* wp = W_hh + (size_t)(r0 + mt * 16 + ln) * H_
                        + wave * 256 + kt * 32 + quad * 8;
      #pragma unroll
      for (int j = 0; j < 8; ++j) {
        float v = wp[j];
        unsigned short h = f2bf(v);
        ahhi[mt][kt][j] = (short)h;
        ahlo[mt][kt][j] = (short)f2bf(v - bf2f(h));
      }
    }
  // A-frags for W_ih: waves 0,1 own the two x K-tiles (i in [32w,32w+32)).
  bf16x8 axhi[2], axlo[2];
  if (wave < 2)
    #pragma unroll
    for (int mt = 0; mt < 2; ++mt) {
      const float* wp = W_ih + (size_t)(r0 + mt * 16 + ln) * I_
                        + wave * 32 + quad * 8;
      #pragma unroll
      for (int j = 0; j < 8; ++j) {
        float v = wp[j];
        unsigned short h = f2bf(v);
        axhi[mt][j] = (short)h;
        axlo[mt][j] = (short)f2bf(v - bf2f(h));
      }
    }
  __syncthreads();

  const int bcol = b0 + ln;

  f32x4 xacc0 = {0.f, 0.f, 0.f, 0.f}, xacc1 = {0.f, 0.f, 0.f, 0.f};
  auto computeX = [&](int t) {        // x-contribution for step t (waves 0,1)
    if (wave < 2) {
      const size_t xo = (((size_t)t * 8 + wave * 4 + quad) * B_ + bcol) * 8;
      bf16x8 bxh = *(const bf16x8*)(xPhi + xo);
      bf16x8 bxl = *(const bf16x8*)(xPlo + xo);
      f32x4 t0 = {0.f, 0.f, 0.f, 0.f}, t1 = {0.f, 0.f, 0.f, 0.f};
      t0 = MFMA16(axhi[0], bxh, t0, 0, 0, 0);
      t1 = MFMA16(axhi[1], bxh, t1, 0, 0, 0);
      t0 = MFMA16(axhi[0], bxl, t0, 0, 0, 0);
      t1 = MFMA16(axhi[1], bxl, t1, 0, 0, 0);
      t0 = MFMA16(axlo[0], bxh, t0, 0, 0, 0);
      t1 = MFMA16(axlo[1], bxh, t1, 0, 0, 0);
      xacc0 = t0; xacc1 = t1;
    }
  };
  computeX(0);

  for (int t = 0; t < T_; ++t) {
    f32x4 acc0 = xacc0, acc1 = xacc1;

    // h contribution: 16 independent 8B LLC atomic loads, then 32 MFMAs
    if (t > 0) {
      const unsigned long long* hp64 =
          (const unsigned long long*)(hP + (size_t)(t - 1) * HSTEP);
      bf16x8 bh[8];
      #pragma unroll
      for (int kt = 0; kt < 8; ++kt) {
        const size_t fo = ((size_t)(wave * 32 + kt * 4 + quad) * B_ + bcol) * 2;
        union { unsigned long long u[2]; bf16x8 v; } U;
        U.u[0] = ldA64(hp64 + fo);
        U.u[1] = ldA64(hp64 + fo + 1);
        bh[kt] = U.v;
      }
      #pragma unroll
      for (int kt = 0; kt < 8; ++kt) {
        acc0 = MFMA16(ahhi[0][kt], bh[kt], acc0, 0, 0, 0);
        acc1 = MFMA16(ahhi[1][kt], bh[kt], acc1, 0, 0, 0);
        acc0 = MFMA16(ahlo[0][kt], bh[kt], acc0, 0, 0, 0);
        acc1 = MFMA16(ahlo[1][kt], bh[kt], acc1, 0, 0, 0);
      }
    }

    // combine K-split partials across waves via LDS
    #pragma unroll
    for (int r = 0; r < 4; ++r) {
      part[wave][r * 64 + lane]       = acc0[r];
      part[wave][(4 + r) * 64 + lane] = acc1[r];
    }
    __syncthreads();

    // epilogue: 256 threads, 2 rows each; 4B LLC atomic store into pack layout
    {
      const int n = tid & 15, rp = tid >> 4;   // col, row-pair
      const int m0 = rp * 2;
      unsigned short o[2];
      #pragma unroll
      for (int rr = 0; rr < 2; ++rr) {
        const int m = m0 + rr;
        const int f = ((m >> 4) * 4 + (m & 3)) * 64 + ((m >> 2) & 3) * 16 + n;
        float s = part[0][f] + part[1][f] + part[2][f] + part[3][f] + biasS[m];
        o[rr] = f2bf(tanhf(s));
      }
      const int R = r0 + m0;
      unsigned* dst = (unsigned*)(hP + (size_t)t * HSTEP
                                  + ((size_t)(R >> 3) * B_ + (b0 + n)) * 8 + (R & 7));
      stA32(dst, (unsigned)o[0] | ((unsigned)o[1] << 16));
    }

    if (t < T_ - 1) {
      computeX(t + 1);               // independent of h -> hidden under barrier
      // ---- flag barrier: __syncthreads drains all waves' LLC stores (vmcnt0)
      __syncthreads();               // also guards part[] reuse
      if (tid == 0) stA32(&bar[g * 32 + rg], (unsigned)(t + 1));
      if (tid < 64) {
        for (;;) {
          unsigned v = (lane < 32) ? ldA32(&bar[g * 32 + lane]) : 0xffffffffu;
          if (__all((int)(v >= (unsigned)(t + 1)))) break;
          __builtin_amdgcn_s_sleep(1);
        }
      }
      __syncthreads();
    }
  }
}

// ---- output projection from pack layout: out[b][t][o] ----
__global__ __launch_bounds__(256, 2) void out_proj(
    const unsigned short* __restrict__ hP, const float* __restrict__ WoT,
    const float* __restrict__ b_out, float* __restrict__ out)
{
  const int t = blockIdx.x;
  const int tid = threadIdx.x;
  const int b  = tid & 127;
  const int oh = tid >> 7;                 // wave-uniform output half
  float a0 = b_out[oh * 6 + 0], a1 = b_out[oh * 6 + 1], a2 = b_out[oh * 6 + 2];
  float a3 = b_out[oh * 6 + 3], a4 = b_out[oh * 6 + 4], a5 = b_out[oh * 6 + 5];
  const unsigned short* hp = hP + (size_t)t * HSTEP + (size_t)b * 8;
  const float4* W4 = (const float4*)WoT;
  for (int kb = 0; kb < 128; ++kb) {
    bf16x8 hv = *(const bf16x8*)(hp + (size_t)kb * (B_ * 8));  // 16B coalesced
    #pragma unroll
    for (int j = 0; j < 8; ++j) {
      const int k = kb * 8 + j;
      float h = bf2f((unsigned short)hv[j]);
      float4 wa = W4[k * 4 + oh * 2];       // wave-uniform
      float4 wb = W4[k * 4 + oh * 2 + 1];
      a0 += wa.x * h; a1 += wa.y * h; a2 += wa.z * h;
      a3 += wa.w * h; a4 += wb.x * h; a5 += wb.y * h;
    }
  }
  float* op = out + ((size_t)b * T_ + t) * O_ + oh * 6;
  op[0] = a0; op[1] = a1; op[2] = a2; op[3] = a3; op[4] = a4; op[5] = a5;
}

// ---- host ----
extern "C" void kernel_launch(void* const* d_in, const int* in_sizes, int n_in,
                              void* d_out, int out_size, void* d_ws, size_t ws_size,
                              hipStream_t stream)
{
  const float* x     = (const float*)d_in[0];
  const float* W_ih  = (const float*)d_in[1];
  const float* W_hh  = (const float*)d_in[2];
  const float* b_ih  = (const float*)d_in[3];
  const float* b_hh  = (const float*)d_in[4];
  const float* W_out = (const float*)d_in[5];
  const float* b_out = (const float*)d_in[6];
  float* out = (float*)d_out;

  unsigned short* hP   = (unsigned short*)d_ws;                 // 134.2 MB
  unsigned short* xPhi = hP + (size_t)T_ * HSTEP;               // 8.4 MB
  unsigned short* xPlo = xPhi + (size_t)T_ * XSTEP;             // 8.4 MB
  float*          WoT  = (float*)(xPlo + (size_t)T_ * XSTEP);   // 64 KB
  unsigned*       bar  = (unsigned*)(WoT + (size_t)H_ * 16);    // 4 KB

  prep_xp  <<<T_,  256, 0, stream>>>(x, xPhi, xPlo);
  prep_misc<<<64,  256, 0, stream>>>(W_out, WoT, bar);
  rnn_mfma <<<256, 256, 0, stream>>>(W_ih, W_hh, b_ih, b_hh, xPhi, xPlo, hP, bar);
  out_proj <<<T_,  256, 0, stream>>>(hP, WoT, b_out, out);
}

// Round 6
// 1895.053 us; speedup vs baseline: 8.9144x; 1.2044x over previous
//
#include <hip/hip_runtime.h>
#include <hip/hip_bf16.h>

#define B_ 128
#define T_ 512
#define I_ 64
#define H_ 1024
#define O_ 12
#define HSTEP (H_ * B_)   // 131072 bf16 elements per timestep of hP
#define XSTEP (I_ * B_)   // 8192 bf16 elements per timestep of xPhi
#define RSLOT 16384       // shorts per ring slot: 128 kb * 16 batches * 8
#define TIMEOUT 2000      // fast-flag poll rounds before sticky fallback

typedef __attribute__((ext_vector_type(8))) short bf16x8;
typedef __attribute__((ext_vector_type(4))) float f32x4;

#define MFMA16 __builtin_amdgcn_mfma_f32_16x16x32_bf16

__device__ __forceinline__ float bf2f(unsigned short s) {
  unsigned u = ((unsigned)s) << 16; float f; __builtin_memcpy(&f, &u, 4); return f;
}
__device__ __forceinline__ unsigned short f2bf(float f) {
  unsigned u; __builtin_memcpy(&u, &f, 4);
  u += 0x7fffu + ((u >> 16) & 1u);   // RNE (finite inputs only here)
  return (unsigned short)(u >> 16);
}

// ---- proven agent-scope (LLC) atomics (rounds 1-3) ----
__device__ __forceinline__ unsigned ldA32(const unsigned* p) {
  return __hip_atomic_load(p, __ATOMIC_RELAXED, __HIP_MEMORY_SCOPE_AGENT);
}
__device__ __forceinline__ void stA32(unsigned* p, unsigned v) {
  __hip_atomic_store(p, v, __ATOMIC_RELAXED, __HIP_MEMORY_SCOPE_AGENT);
}
__device__ __forceinline__ unsigned long long ldA64(const unsigned long long* p) {
  return __hip_atomic_load(p, __ATOMIC_RELAXED, __HIP_MEMORY_SCOPE_AGENT);
}

// ---- XCD-local primitives (sc0: bypass L1, served by this XCD's L2) ----
// Speed-only: every use has a proven-slow dual. Never load-bearing for
// correctness or termination.
__device__ __forceinline__ void store32_sc0(unsigned* p, unsigned v) {
  asm volatile("global_store_dword %0, %1, off sc0" :: "v"(p), "v"(v) : "memory");
}
__device__ __forceinline__ unsigned poll_sc0(const unsigned* p) {
  unsigned v;
  asm volatile("global_load_dword %0, %1, off sc0\n\ts_waitcnt vmcnt(0)"
               : "=v"(v) : "v"(p) : "memory");
  return v;
}
__device__ __forceinline__ bf16x8 load16_sc0(const void* p) {
  bf16x8 v;
  asm volatile("global_load_dwordx4 %0, %1, off sc0" : "=v"(v) : "v"(p));
  return v;
}
__device__ __forceinline__ void waitv8(bf16x8& v0, bf16x8& v1, bf16x8& v2, bf16x8& v3,
                                       bf16x8& v4, bf16x8& v5, bf16x8& v6, bf16x8& v7) {
  asm volatile("s_waitcnt vmcnt(0)"
               : "+v"(v0), "+v"(v1), "+v"(v2), "+v"(v3),
                 "+v"(v4), "+v"(v5), "+v"(v6), "+v"(v7) :: "memory");
}

// ---- prep: x[b][t][i] fp32 -> pack-layout bf16 plane xPhi[t][i/8][b][i%8] ----
__global__ void prep_xp(const float* __restrict__ x,
                        unsigned short* __restrict__ xPhi) {
  const int t = blockIdx.x;
  for (int u = threadIdx.x; u < 1024; u += 256) {   // u = ib*128 + b
    const int ib = u >> 7, b = u & 127;
    const float* src = x + ((size_t)b * T_ + t) * I_ + ib * 8;
    bf16x8 hi;
    #pragma unroll
    for (int j = 0; j < 8; ++j) hi[j] = (short)f2bf(src[j]);
    *(bf16x8*)(xPhi + ((size_t)t * 1024 + u) * 8) = hi;
  }
}

// ---- prep: zero flags + W_out transposed/padded WoT[k][16] ----
// bar uints: [0..255] fast flags (sc0 medium), [256..511] slow flags (LLC).
__global__ void prep_misc(const float* __restrict__ W_out, float* __restrict__ WoT,
                          unsigned* __restrict__ bar) {
  const int idx = blockIdx.x * 256 + threadIdx.x;   // 64 blocks -> 16384 threads
  if (idx < 1024) bar[idx] = 0u;
  const int k = idx >> 4, s = idx & 15;
  float v = 0.0f;
  if (s < 6)                 v = W_out[s * H_ + k];
  else if (s >= 8 && s < 14) v = W_out[(s - 2) * H_ + k];
  WoT[idx] = v;
}

// ---- persistent MFMA recurrence ----
// g = bid&7 (batch group; XCD-pure if dispatch is round-robin), rg = bid>>3.
// h exchange via 2-deep rings: rF (sc0, XCD-L2) + rS (LLC, proven) — producers
// dual-publish both plus dual flags; consumers try fast with bounded timeout,
// flip sticky-slow per block on failure. Full history hP written with plain
// cached stores for out_proj only.
__global__ __launch_bounds__(256, 1) void rnn_mfma(
    const float* __restrict__ W_ih, const float* __restrict__ W_hh,
    const float* __restrict__ b_ih, const float* __restrict__ b_hh,
    const unsigned short* __restrict__ xPhi, unsigned short* __restrict__ hP,
    unsigned short* __restrict__ rF, unsigned short* __restrict__ rS,
    unsigned* __restrict__ bar)
{
  __shared__ float part[4][544];    // 8 rows x 68 (padded: conflict-free)
  __shared__ float biasS[32];
  __shared__ unsigned modeS;        // 1 = fast, one-way latch to 0
  const int tid = threadIdx.x, bid = blockIdx.x;
  const int wave = tid >> 6, lane = tid & 63, quad = lane >> 4, ln = lane & 15;
  const int g = bid & 7, rg = bid >> 3;
  const int r0 = rg * 32, b0 = g * 16;
  if (tid < 32) biasS[tid] = b_ih[r0 + tid] + b_hh[r0 + tid];
  if (tid == 0) modeS = 1u;

  // A-frags for W_hh (hi/lo split -> fp32-grade W precision), loaded once.
  bf16x8 ahhi[2][8], ahlo[2][8];
  #pragma unroll
  for (int mt = 0; mt < 2; ++mt)
    #pragma unroll
    for (int kt = 0; kt < 8; ++kt) {
      const float* wp = W_hh + (size_t)(r0 + mt * 16 + ln) * H_
                        + wave * 256 + kt * 32 + quad * 8;
      #pragma unroll
      for (int j = 0; j < 8; ++j) {
        float v = wp[j];
        unsigned short h = f2bf(v);
        ahhi[mt][kt][j] = (short)h;
        ahlo[mt][kt][j] = (short)f2bf(v - bf2f(h));
      }
    }
  // A-frags for W_ih: waves 0,1 own the two x K-tiles (i in [32w,32w+32)).
  bf16x8 axhi[2], axlo[2];
  if (wave < 2)
    #pragma unroll
    for (int mt = 0; mt < 2; ++mt) {
      const float* wp = W_ih + (size_t)(r0 + mt * 16 + ln) * I_
                        + wave * 32 + quad * 8;
      #pragma unroll
      for (int j = 0; j < 8; ++j) {
        float v = wp[j];
        unsigned short h = f2bf(v);
        axhi[mt][j] = (short)h;
        axlo[mt][j] = (short)f2bf(v - bf2f(h));
      }
    }
  __syncthreads();
  unsigned mode = 1u;               // block-uniform; updated only at barriers

  const int bcol = b0 + ln;
  unsigned short* rFg = rF + (size_t)g * 2 * RSLOT;
  unsigned short* rSg = rS + (size_t)g * 2 * RSLOT;

  f32x4 xacc0 = {0.f, 0.f, 0.f, 0.f}, xacc1 = {0.f, 0.f, 0.f, 0.f};
  auto computeX = [&](int t) {      // x-contribution for step t (waves 0,1)
    if (wave < 2) {
      const size_t xo = (((size_t)t * 8 + wave * 4 + quad) * B_ + bcol) * 8;
      bf16x8 bxh = *(const bf16x8*)(xPhi + xo);
      f32x4 t0 = {0.f, 0.f, 0.f, 0.f}, t1 = {0.f, 0.f, 0.f, 0.f};
      t0 = MFMA16(axhi[0], bxh, t0, 0, 0, 0);
      t0 = MFMA16(axlo[0], bxh, t0, 0, 0, 0);
      t1 = MFMA16(axhi[1], bxh, t1, 0, 0, 0);
      t1 = MFMA16(axlo[1], bxh, t1, 0, 0, 0);
      xacc0 = t0; xacc1 = t1;
    }
  };
  computeX(0);

  for (int t = 0; t < T_; ++t) {
    // split accumulators: hi-chain (A) and lo-chain (B) -> halved dep chains
    f32x4 accA0 = xacc0, accA1 = xacc1;
    f32x4 accB0 = {0.f, 0.f, 0.f, 0.f}, accB1 = {0.f, 0.f, 0.f, 0.f};

    if (t > 0) {
      const int soff = ((wave * 32 + quad) * 16 + ln) * 8;   // shorts
      bf16x8 bh[8];
      if (mode) {
        const unsigned short* slot = rFg + ((t - 1) & 1) * RSLOT + soff;
        #pragma unroll
        for (int kt = 0; kt < 8; ++kt)
          bh[kt] = load16_sc0(slot + kt * 512);              // XCD-L2 hits
        waitv8(bh[0], bh[1], bh[2], bh[3], bh[4], bh[5], bh[6], bh[7]);
      } else {
        const unsigned long long* slot =
            (const unsigned long long*)(rSg + ((t - 1) & 1) * RSLOT + soff);
        #pragma unroll
        for (int kt = 0; kt < 8; ++kt) {
          union { unsigned long long u[2]; bf16x8 v; } U;
          U.u[0] = ldA64(slot + kt * 128);
          U.u[1] = ldA64(slot + kt * 128 + 1);
          bh[kt] = U.v;
        }
      }
      #pragma unroll
      for (int kt = 0; kt < 8; ++kt) {
        accA0 = MFMA16(ahhi[0][kt], bh[kt], accA0, 0, 0, 0);
        accA1 = MFMA16(ahhi[1][kt], bh[kt], accA1, 0, 0, 0);
        accB0 = MFMA16(ahlo[0][kt], bh[kt], accB0, 0, 0, 0);
        accB1 = MFMA16(ahlo[1][kt], bh[kt], accB1, 0, 0, 0);
      }
    }

    // combine K-split partials across waves via LDS (rows padded to 68)
    #pragma unroll
    for (int r = 0; r < 4; ++r) {
      part[wave][r * 68 + lane]       = accA0[r] + accB0[r];
      part[wave][(4 + r) * 68 + lane] = accA1[r] + accB1[r];
    }
    __syncthreads();

    // epilogue: 256 threads, 2 rows each; dual-publish rings + history store
    {
      const int n = tid & 15, rp = tid >> 4;
      const int m0 = rp * 2;
      unsigned short o[2];
      #pragma unroll
      for (int rr = 0; rr < 2; ++rr) {
        const int m = m0 + rr;
        const int f = ((m >> 4) * 4 + (m & 3)) * 68 + ((m >> 2) & 3) * 16 + n;
        float s = part[0][f] + part[1][f] + part[2][f] + part[3][f] + biasS[m];
        o[rr] = f2bf(tanhf(s));
      }
      const unsigned pk = (unsigned)o[0] | ((unsigned)o[1] << 16);
      const int R = r0 + m0;
      // history (plain cached write-back; consumed only by out_proj)
      *(unsigned*)(hP + (size_t)t * HSTEP
                   + ((size_t)(R >> 3) * B_ + (b0 + n)) * 8 + (R & 7)) = pk;
      // rings (group-local batch index n)
      const int soff = ((R >> 3) * 16 + n) * 8 + (R & 7);
      store32_sc0((unsigned*)(rFg + (t & 1) * RSLOT + soff), pk);
      stA32      ((unsigned*)(rSg + (t & 1) * RSLOT + soff), pk);
    }

    if (t < T_ - 1) {
      computeX(t + 1);                                   // independent of h_t
      asm volatile("s_waitcnt vmcnt(0)" ::: "memory");   // all publishes ack'd
      __syncthreads();                                   // also guards part[]
      if (tid == 0) {
        store32_sc0(&bar[g * 32 + rg],      (unsigned)(t + 1));   // fast flag
        stA32      (&bar[256 + g * 32 + rg], (unsigned)(t + 1));  // slow flag
      }
      if (tid < 64) {
        int ok = 0;
        if (mode) {
          for (int it = 0; it < TIMEOUT && !ok; ++it) {
            unsigned v = (lane < 32) ? poll_sc0(&bar[g * 32 + lane]) : 0xffffffffu;
            ok = __all((int)(v >= (unsigned)(t + 1)));
          }
        }
        if (!ok) {                 // sticky fallback to proven LLC protocol
          if (tid == 0) modeS = 0u;
          for (;;) {
            unsigned v = (lane < 32) ? ldA32(&bar[256 + g * 32 + lane]) : 0xffffffffu;
            if (__all((int)(v >= (unsigned)(t + 1)))) break;
            __builtin_amdgcn_s_sleep(1);
          }
        }
      }
      __syncthreads();
      mode = modeS;                // block-uniform mode for next step's loads
    }
  }
}

// ---- output projection from pack layout: out[b][t][o] ----
__global__ __launch_bounds__(256, 2) void out_proj(
    const unsigned short* __restrict__ hP, const float* __restrict__ WoT,
    const float* __restrict__ b_out, float* __restrict__ out)
{
  const int t = blockIdx.x;
  const int tid = threadIdx.x;
  const int b  = tid & 127;
  const int oh = tid >> 7;                 // wave-uniform output half
  float a0 = b_out[oh * 6 + 0], a1 = b_out[oh * 6 + 1], a2 = b_out[oh * 6 + 2];
  float a3 = b_out[oh * 6 + 3], a4 = b_out[oh * 6 + 4], a5 = b_out[oh * 6 + 5];
  const unsigned short* hp = hP + (size_t)t * HSTEP + (size_t)b * 8;
  const float4* W4 = (const float4*)WoT;
  for (int kb = 0; kb < 128; ++kb) {
    bf16x8 hv = *(const bf16x8*)(hp + (size_t)kb * (B_ * 8));  // 16B coalesced
    #pragma unroll
    for (int j = 0; j < 8; ++j) {
      const int k = kb * 8 + j;
      float h = bf2f((unsigned short)hv[j]);
      float4 wa = W4[k * 4 + oh * 2];       // wave-uniform
      float4 wb = W4[k * 4 + oh * 2 + 1];
      a0 += wa.x * h; a1 += wa.y * h; a2 += wa.z * h;
      a3 += wa.w * h; a4 += wb.x * h; a5 += wb.y * h;
    }
  }
  float* op = out + ((size_t)b * T_ + t) * O_ + oh * 6;
  op[0] = a0; op[1] = a1; op[2] = a2; op[3] = a3; op[4] = a4; op[5] = a5;
}

// ---- host ----
extern "C" void kernel_launch(void* const* d_in, const int* in_sizes, int n_in,
                              void* d_out, int out_size, void* d_ws, size_t ws_size,
                              hipStream_t stream)
{
  const float* x     = (const float*)d_in[0];
  const float* W_ih  = (const float*)d_in[1];
  const float* W_hh  = (const float*)d_in[2];
  const float* b_ih  = (const float*)d_in[3];
  const float* b_hh  = (const float*)d_in[4];
  const float* W_out = (const float*)d_in[5];
  const float* b_out = (const float*)d_in[6];
  float* out = (float*)d_out;

  unsigned short* hP   = (unsigned short*)d_ws;                  // 134.2 MB
  unsigned short* xPhi = hP + (size_t)T_ * HSTEP;                // 8.4 MB
  float*          WoT  = (float*)(xPhi + (size_t)T_ * XSTEP);    // 64 KB
  unsigned short* rF   = (unsigned short*)(WoT + (size_t)H_ * 16); // 512 KB
  unsigned short* rS   = rF + (size_t)8 * 2 * RSLOT;             // 512 KB
  unsigned*       bar  = (unsigned*)(rS + (size_t)8 * 2 * RSLOT); // 4 KB

  prep_xp  <<<T_,  256, 0, stream>>>(x, xPhi);
  prep_misc<<<64,  256, 0, stream>>>(W_out, WoT, bar);
  rnn_mfma <<<256, 256, 0, stream>>>(W_ih, W_hh, b_ih, b_hh, xPhi, hP, rF, rS, bar);
  out_proj <<<T_,  256, 0, stream>>>(hP, WoT, b_out, out);
}